// Round 6
// baseline (62.995 us; speedup 1.0000x reference)
//
#include <hip/hip_runtime.h>

#define D256 256
#define KT 8
#define S_SEQ 1024
#define OUTSEQ 512

// ---------------- prep: transpose/pack tables ----------------
// MW[j][o]   = {M[o][j], res_W[o][j]}
// PIt2[j][i] = {P[i][j], 1/p}, p = i*256+j+2   (cb2 derived in-kernel)
__global__ __launch_bounds__(256) void k_prep(const float* __restrict__ M,
                                              const float* __restrict__ resW,
                                              const float* __restrict__ P,
                                              float2* __restrict__ MW,
                                              float2* __restrict__ PIt2) {
  const int j = blockIdx.x;
  const int t = threadIdx.x;
  MW[j * D256 + t] = make_float2(M[t * D256 + j], resW[t * D256 + j]);
  const float p = (float)(t * D256 + j + 2);
  PIt2[j * D256 + t] = make_float2(P[t * D256 + j], 1.0f / p);
}

// ---------------- fused k_AB: GEMM -> LN -> cos-einsum, Z never leaves LDS --
// grid 256 (k-tiles of 8), 1024 threads = (j-quarter h) x (col i)
__global__ __launch_bounds__(1024, 4) void k_AB(const float* __restrict__ x,
                                                const float2* __restrict__ MW,
                                                const float2* __restrict__ PIt2,
                                                const float* __restrict__ gamma,
                                                const float* __restrict__ beta,
                                                float* __restrict__ T,
                                                float* __restrict__ rfeat) {
  __shared__ float Xs[D256][12];         // [col][row] padded: b128 rows, 12 KB
  __shared__ float2 red2[4][KT][D256];   // 64 KB: {aM, aR} then {accT, -}
  __shared__ float mu_s[KT], rs_s[KT];
  const int tid = threadIdx.x;
  const int i = tid & 255;
  const int h = tid >> 8;               // j-quarter, wave-uniform
  const int j0 = h * 64;
  const int k0 = blockIdx.x * KT;

  // stage x tile transposed: [col][row]
  Xs[i][h]     = x[(k0 + h) * D256 + i];
  Xs[i][h + 4] = x[(k0 + h + 4) * D256 + i];
  __syncthreads();

  // ---- phase A: partial x@M^T and x@resW^T over j-quarter ----
  float aM[KT], aR[KT];
  #pragma unroll
  for (int r = 0; r < KT; ++r) { aM[r] = 0.f; aR[r] = 0.f; }
  {
    const float2* mwp = MW + i;
    #pragma unroll 8
    for (int jj = 0; jj < 64; ++jj) {
      const int j = j0 + jj;
      const float2 mw = mwp[j * D256];
      const float4 z0 = *(const float4*)&Xs[j][0];   // broadcast b128
      const float4 z1 = *(const float4*)&Xs[j][4];
      aM[0] = fmaf(z0.x, mw.x, aM[0]); aR[0] = fmaf(z0.x, mw.y, aR[0]);
      aM[1] = fmaf(z0.y, mw.x, aM[1]); aR[1] = fmaf(z0.y, mw.y, aR[1]);
      aM[2] = fmaf(z0.z, mw.x, aM[2]); aR[2] = fmaf(z0.z, mw.y, aR[2]);
      aM[3] = fmaf(z0.w, mw.x, aM[3]); aR[3] = fmaf(z0.w, mw.y, aR[3]);
      aM[4] = fmaf(z1.x, mw.x, aM[4]); aR[4] = fmaf(z1.x, mw.y, aR[4]);
      aM[5] = fmaf(z1.y, mw.x, aM[5]); aR[5] = fmaf(z1.y, mw.y, aR[5]);
      aM[6] = fmaf(z1.z, mw.x, aM[6]); aR[6] = fmaf(z1.z, mw.y, aR[6]);
      aM[7] = fmaf(z1.w, mw.x, aM[7]); aR[7] = fmaf(z1.w, mw.y, aR[7]);
    }
  }

  // single-round cross-quarter reduce of {aM, aR}
  #pragma unroll
  for (int r = 0; r < KT; ++r) red2[h][r][i] = make_float2(aM[r], aR[r]);
  __syncthreads();
  #pragma unroll
  for (int p = 0; p < 2; ++p) {
    const int r = h * 2 + p;
    const float2 a0 = red2[0][r][i], a1 = red2[1][r][i];
    const float2 a2 = red2[2][r][i], a3 = red2[3][r][i];
    rfeat[(k0 + r) * D256 + i] = a0.y + a1.y + a2.y + a3.y;
    Xs[i][r] = a0.x + a1.x + a2.x + a3.x;       // pre-LN Z
  }
  __syncthreads();

  // LN stats: wave w reduces row w
  const int w = tid >> 6, lane = tid & 63;
  if (w < KT) {
    float s = 0.f, sq = 0.f;
    #pragma unroll
    for (int l = 0; l < 4; ++l) {
      const float v = Xs[lane + 64 * l][w];
      s += v;
      sq = fmaf(v, v, sq);
    }
    #pragma unroll
    for (int off = 32; off; off >>= 1) {
      s += __shfl_down(s, off);
      sq += __shfl_down(sq, off);
    }
    if (lane == 0) {
      const float m = s * (1.0f / 256.0f);
      const float var = sq * (1.0f / 256.0f) - m * m;
      mu_s[w] = m;
      rs_s[w] = rsqrtf(var + 1e-5f);
    }
  }
  __syncthreads();
  {
    const float g = gamma[i], be = beta[i];
    #pragma unroll
    for (int p = 0; p < 2; ++p) {
      const int r = h + 4 * p;
      Xs[i][r] = (Xs[i][r] - mu_s[r]) * rs_s[r] * g + be;
    }
  }
  __syncthreads();

  // ---- phase B: T[k,i] = sum_j Z[k,j]*P[i,j]*cos(2pi*k/p_ij), Chebyshev ----
  float accT[KT] = {};
  const float kf0 = (float)k0, kf1 = (float)(k0 + 1);
  {
    const float2* pip = PIt2 + i;
    #pragma unroll 8
    for (int jj = 0; jj < 64; ++jj) {
      const int j = j0 + jj;
      const float2 pi = pip[j * D256];               // {P, 1/p}
      const float4 z0 = *(const float4*)&Xs[j][0];   // broadcast b128
      const float4 z1 = *(const float4*)&Xs[j][4];
      const float cs = __builtin_amdgcn_cosf(pi.y);  // cos(2pi/p), rev arg
      const float cb2 = cs + cs;
      const float r0 = __builtin_amdgcn_fractf(kf0 * pi.y);
      const float r1 = __builtin_amdgcn_fractf(kf1 * pi.y);
      float c0 = __builtin_amdgcn_cosf(r0);
      float c1 = __builtin_amdgcn_cosf(r1);
      accT[0] = fmaf(z0.x * pi.x, c0, accT[0]);
      accT[1] = fmaf(z0.y * pi.x, c1, accT[1]);
      float c2;
      c2 = fmaf(cb2, c1, -c0); accT[2] = fmaf(z0.z * pi.x, c2, accT[2]); c0 = c1; c1 = c2;
      c2 = fmaf(cb2, c1, -c0); accT[3] = fmaf(z0.w * pi.x, c2, accT[3]); c0 = c1; c1 = c2;
      c2 = fmaf(cb2, c1, -c0); accT[4] = fmaf(z1.x * pi.x, c2, accT[4]); c0 = c1; c1 = c2;
      c2 = fmaf(cb2, c1, -c0); accT[5] = fmaf(z1.y * pi.x, c2, accT[5]); c0 = c1; c1 = c2;
      c2 = fmaf(cb2, c1, -c0); accT[6] = fmaf(z1.z * pi.x, c2, accT[6]); c0 = c1; c1 = c2;
      c2 = fmaf(cb2, c1, -c0); accT[7] = fmaf(z1.w * pi.x, c2, accT[7]);
    }
  }
  #pragma unroll
  for (int r = 0; r < KT; ++r) red2[h][r][i].x = accT[r];
  __syncthreads();
  #pragma unroll
  for (int p = 0; p < 2; ++p) {
    const int r = h * 2 + p;
    T[(k0 + r) * D256 + i] =
        red2[0][r][i].x + red2[1][r][i].x + red2[2][r][i].x + red2[3][r][i].x;
  }
}

// ---------------- stage C1: split-s partial GEMM, t-tile 16 ----------------
// grid = b(2) x tt(32) x sc(8) = 512 blocks; 256 thr = d
__global__ __launch_bounds__(256) void k_C1(const float* __restrict__ T,
                                            const float* __restrict__ rfeat,
                                            const float* __restrict__ Linker,
                                            const float* __restrict__ rLinker,
                                            float* __restrict__ part) {
  __shared__ float Ls[128][16];
  __shared__ float rLs[128][16];
  const int bid = blockIdx.x;
  const int sc = bid & 7;
  const int tt = (bid >> 3) & 31;
  const int b  = bid >> 8;
  const int t0 = tt * 16;
  const int s0 = sc * 128;
  const int d  = threadIdx.x;

  // stage Linker chunks: 128 rows x 16 cols each, float4 x2 per thread/table
  #pragma unroll
  for (int it = 0; it < 2; ++it) {
    const int idx = threadIdx.x + it * 256;     // 0..511
    const int row = idx >> 2;
    const int c4  = (idx & 3) * 4;
    *(float4*)&Ls[row][c4]  = *(const float4*)&Linker[(s0 + row) * OUTSEQ + t0 + c4];
    *(float4*)&rLs[row][c4] = *(const float4*)&rLinker[(s0 + row) * OUTSEQ + t0 + c4];
  }
  __syncthreads();

  float acc[16] = {};
  const float* Tp = &T[(b * S_SEQ + s0) * D256 + d];
  const float* Rp = &rfeat[(b * S_SEQ + s0) * D256 + d];
  #pragma unroll 4
  for (int s = 0; s < 128; ++s) {
    const float tv = Tp[s * D256];
    const float rv = Rp[s * D256];
    #pragma unroll
    for (int q = 0; q < 4; ++q) {
      const float4 l = *(const float4*)&Ls[s][q * 4];    // broadcast
      const float4 r = *(const float4*)&rLs[s][q * 4];
      acc[q * 4 + 0] = fmaf(tv, l.x, acc[q * 4 + 0]);
      acc[q * 4 + 0] = fmaf(rv, r.x, acc[q * 4 + 0]);
      acc[q * 4 + 1] = fmaf(tv, l.y, acc[q * 4 + 1]);
      acc[q * 4 + 1] = fmaf(rv, r.y, acc[q * 4 + 1]);
      acc[q * 4 + 2] = fmaf(tv, l.z, acc[q * 4 + 2]);
      acc[q * 4 + 2] = fmaf(rv, r.z, acc[q * 4 + 2]);
      acc[q * 4 + 3] = fmaf(tv, l.w, acc[q * 4 + 3]);
      acc[q * 4 + 3] = fmaf(rv, r.w, acc[q * 4 + 3]);
    }
  }

  const int rowbase = b * 512 + t0;
  #pragma unroll
  for (int u = 0; u < 16; ++u)
    part[(((sc << 10) + rowbase + u) << 8) + d] = acc[u];
}

// ---------------- stage C2: reduce the 8 s-chunk partials ----------------
__global__ __launch_bounds__(256) void k_C2(const float* __restrict__ part,
                                            float* __restrict__ out) {
  const int row = blockIdx.x;   // 0..1023
  const int d   = threadIdx.x;
  float s = 0.f;
  #pragma unroll
  for (int sc = 0; sc < 8; ++sc)
    s += part[(((sc << 10) + row) << 8) + d];
  out[(row << 8) + d] = s;
}

extern "C" void kernel_launch(void* const* d_in, const int* in_sizes, int n_in,
                              void* d_out, int out_size, void* d_ws, size_t ws_size,
                              hipStream_t stream) {
  const float* x       = (const float*)d_in[0];
  const float* M       = (const float*)d_in[1];
  const float* P       = (const float*)d_in[2];
  const float* Linker  = (const float*)d_in[3];
  const float* gamma   = (const float*)d_in[4];
  const float* beta    = (const float*)d_in[5];
  const float* resW    = (const float*)d_in[6];
  const float* rLinker = (const float*)d_in[7];
  float* out = (float*)d_out;

  char* ws = (char*)d_ws;
  float2* MW    = (float2*)(ws);                        // 0.5 MB
  float2* PIt2  = (float2*)(ws + 512 * 1024);           // 0.5 MB
  float*  T     = (float*)(ws + 1024 * 1024);           // 2 MB
  float*  rfeat = (float*)(ws + 3072 * 1024);           // 2 MB
  float*  part  = (float*)(ws + 5120 * 1024);           // 8 MB

  hipLaunchKernelGGL(k_prep, dim3(256),  dim3(256),  0, stream, M, resW, P, MW, PIt2);
  hipLaunchKernelGGL(k_AB,   dim3(256),  dim3(1024), 0, stream, x, MW, PIt2, gamma, beta, T, rfeat);
  hipLaunchKernelGGL(k_C1,   dim3(512),  dim3(256),  0, stream, T, rfeat, Linker, rLinker, part);
  hipLaunchKernelGGL(k_C2,   dim3(1024), dim3(256),  0, stream, part, out);
}